// Round 5
// baseline (243.149 us; speedup 1.0000x reference)
//
#include <hip/hip_runtime.h>
#include <hip/hip_bf16.h>

typedef __hip_bfloat16 bf16;
typedef __attribute__((ext_vector_type(8))) short bf16x8;
typedef __attribute__((ext_vector_type(4))) float f32x4;

#define T_SEQ 2048
#define NHEADS 16
#define DK 64
#define DMODEL 1024

__device__ inline void load_lds16(const void* g, void* l) {
    __builtin_amdgcn_global_load_lds((const __attribute__((address_space(1))) void*)g,
                                     (__attribute__((address_space(3))) void*)l, 16, 0, 0);
}

// ---------------- RoPE cos/sin table: tab[t][i] = (cos,sin)(t * 1000^(-i/32))
__global__ void rope_table_k(float2* __restrict__ tab) {
    int idx = blockIdx.x * blockDim.x + threadIdx.x;   // 0..65535
    int t = idx >> 5, i = idx & 31;
    float inv = exp2f(-0.31143075889f * (float)i);     // 1000^(-i/32)
    float s, c;
    __sincosf((float)t * inv, &s, &c);
    tab[idx] = make_float2(c, s);
}

// ---------------- fp32 -> bf16 convert: x + all four weights, one launch ----
__global__ void cvt_all(const float* __restrict__ x,  const float* __restrict__ wq,
                        const float* __restrict__ wk, const float* __restrict__ wv,
                        const float* __restrict__ wo, bf16* __restrict__ xb,
                        bf16* __restrict__ wqkvb, bf16* __restrict__ wob) {
    int i = blockIdx.x * blockDim.x + threadIdx.x;   // 0 .. 2M-1 (float4 units)
    const float* src; bf16* dst; int off;
    if (i < (1 << 20)) { src = x; dst = xb; off = i; }
    else {
        int j = i - (1 << 20);
        int seg = j >> 18; off = j & ((1 << 18) - 1);
        src = (seg == 0) ? wq : (seg == 1) ? wk : (seg == 2) ? wv : wo;
        dst = (seg < 3) ? (wqkvb + ((size_t)seg << 20)) : wob;
    }
    float4 f = ((const float4*)src)[off];
    ushort4 o;
    o.x = __bfloat16_as_ushort(__float2bfloat16(f.x));
    o.y = __bfloat16_as_ushort(__float2bfloat16(f.y));
    o.z = __bfloat16_as_ushort(__float2bfloat16(f.z));
    o.w = __bfloat16_as_ushort(__float2bfloat16(f.w));
    ((ushort4*)dst)[off] = o;
}

// ---------------- GEMM1: qkv = x * Wqkv^T, fused RoPE + head split ----------
// v14 (base = round-3 single-buffer loop; dbuf reverted, it regressed):
//  (a) LDS 16B-block XOR swizzle (cc ^ (row>>1)&3): 8-way ds_read_b128 bank
//      conflict -> 2-way (free).  Linear DMA dest + pre-swizzled global src.
//  (b) RoPE cos/sin from precomputed table (identical values) - kills 64
//      __sincosf per lane in the epilogue.
//  (c) seg==2 (v) blocks compute the TRANSPOSED tile via swapped MFMA
//      operands, so vt stores are 32B-contiguous instead of a 64-line scatter.
// C rows = b*2048+t, cols e in [0,3072): seg 0=q (rope'd, pre-scaled by
// log2(e)/8), 1=k (rope'd) -> qb/kb [bh][t][dk], seg 2=v -> vt [bh][dk][t].
__global__ __launch_bounds__(256) void gemm_qkv_rope(const bf16* __restrict__ A,
                                                     const bf16* __restrict__ B,
                                                     const float2* __restrict__ tab,
                                                     bf16* __restrict__ qb,
                                                     bf16* __restrict__ kb,
                                                     bf16* __restrict__ vt) {
    const int K = 1024;
    __shared__ bf16 As[128 * 32];
    __shared__ bf16 Bs[128 * 32];
    const int tid  = threadIdx.x;
    const int lane = tid & 63;
    const int wave = tid >> 6;
    const int l16  = lane & 15;
    const int quad = lane >> 4;
    const int wy = wave >> 1, wx = wave & 1;
    const int brow = blockIdx.y * 128;
    const int bcol = blockIdx.x * 128;
    const int seg  = bcol >> 10;                      // uniform per block

    f32x4 acc[4][4] = {};

    for (int k0 = 0; k0 < K; k0 += 32) {
#pragma unroll
        for (int i = 0; i < 2; ++i) {
            int j   = tid + 256 * i;
            int row = j >> 2;
            int cc  = (j & 3) ^ ((row >> 1) & 3);     // pre-swizzled source
            load_lds16(A + (size_t)(brow + row) * K + k0 + cc * 8, (char*)As + j * 16);
            load_lds16(B + (size_t)(bcol + row) * K + k0 + cc * 8, (char*)Bs + j * 16);
        }
        __syncthreads();
        bf16x8 af[4], bq[4];
#pragma unroll
        for (int i = 0; i < 4; ++i) {
            int row = wy * 64 + i * 16 + l16;
            af[i] = *(const bf16x8*)(As + row * 32 + (quad ^ ((row >> 1) & 3)) * 8);
        }
#pragma unroll
        for (int j = 0; j < 4; ++j) {
            int row = wx * 64 + j * 16 + l16;
            bq[j] = *(const bf16x8*)(Bs + row * 32 + (quad ^ ((row >> 1) & 3)) * 8);
        }
        if (seg < 2) {
#pragma unroll
            for (int i = 0; i < 4; ++i)
#pragma unroll
                for (int j = 0; j < 4; ++j)
                    acc[i][j] = __builtin_amdgcn_mfma_f32_16x16x32_bf16(af[i], bq[j], acc[i][j], 0, 0, 0);
        } else {
            // swapped operands: C' = W * x^T (transposed tile) so the lane
            // dim (l16) lands on t -> coalesced vt stores
#pragma unroll
            for (int i = 0; i < 4; ++i)
#pragma unroll
                for (int j = 0; j < 4; ++j)
                    acc[i][j] = __builtin_amdgcn_mfma_f32_16x16x32_bf16(bq[j], af[i], acc[i][j], 0, 0, 0);
        }
        __syncthreads();
    }
    const int hh = ((bcol & 1023) >> 6) + wx;         // head index
    if (seg < 2) {
        bf16* dst = seg ? kb : qb;
        // q pre-scaled so attn computes p = exp2(q'.k) directly
        const float osc = seg ? 1.0f : 0.18033688011112042f;  // log2(e)/8
#pragma unroll
        for (int j = 0; j < 4; ++j) {
            const int fidx = j * 8 + (l16 >> 1);      // d>>1 within head
#pragma unroll
            for (int i = 0; i < 4; ++i)
#pragma unroll
                for (int r = 0; r < 4; ++r) {
                    int row = brow + wy * 64 + i * 16 + quad * 4 + r;
                    int t = row & (T_SEQ - 1), bi = row >> 11;
                    float2 cs = tab[t * 32 + fidx];
                    float v = acc[i][j][r];
                    float p = __shfl_xor(v, 1);
                    float res = (l16 & 1) ? fmaf(p, cs.y, v * cs.x)
                                          : fmaf(-p, cs.y, v * cs.x);
                    dst[((size_t)(bi * NHEADS + hh) * T_SEQ + t) * DK + j * 16 + l16] =
                        __float2bfloat16(res * osc);
                }
        }
    } else {
        // transposed fragment: m-dim (quad*4+r over j) = d, n-dim (l16 over i) = t
#pragma unroll
        for (int j = 0; j < 4; ++j)
#pragma unroll
            for (int i = 0; i < 4; ++i)
#pragma unroll
                for (int r = 0; r < 4; ++r) {
                    int d    = j * 16 + quad * 4 + r;           // dk within head
                    int tcol = brow + wy * 64 + i * 16 + l16;
                    int t = tcol & (T_SEQ - 1), bi = tcol >> 11;
                    vt[((size_t)(bi * NHEADS + hh) * DK + d) * T_SEQ + t] =
                        __float2bfloat16(acc[i][j][r]);
                }
    }
}

// ---------------- GEMM: C[M,N] = A[M,K] * B[N,K]^T (fp32 out) ----------------
// v14: single-buffer loop + same LDS XOR swizzle as gemm_qkv_rope.
__global__ __launch_bounds__(256) void gemm_bt(const bf16* __restrict__ A,
                                               const bf16* __restrict__ B,
                                               float* __restrict__ C,
                                               int M, int N, int K) {
    __shared__ bf16 As[128 * 32];
    __shared__ bf16 Bs[128 * 32];
    const int tid  = threadIdx.x;
    const int lane = tid & 63;
    const int wave = tid >> 6;
    const int l16  = lane & 15;
    const int quad = lane >> 4;
    const int wy = wave >> 1, wx = wave & 1;
    const int brow = blockIdx.y * 128;
    const int bcol = blockIdx.x * 128;

    f32x4 acc[4][4] = {};

    for (int k0 = 0; k0 < K; k0 += 32) {
#pragma unroll
        for (int i = 0; i < 2; ++i) {
            int j   = tid + 256 * i;
            int row = j >> 2;
            int cc  = (j & 3) ^ ((row >> 1) & 3);
            load_lds16(A + (size_t)(brow + row) * K + k0 + cc * 8, (char*)As + j * 16);
            load_lds16(B + (size_t)(bcol + row) * K + k0 + cc * 8, (char*)Bs + j * 16);
        }
        __syncthreads();
        bf16x8 af[4], bq[4];
#pragma unroll
        for (int i = 0; i < 4; ++i) {
            int row = wy * 64 + i * 16 + l16;
            af[i] = *(const bf16x8*)(As + row * 32 + (quad ^ ((row >> 1) & 3)) * 8);
        }
#pragma unroll
        for (int j = 0; j < 4; ++j) {
            int row = wx * 64 + j * 16 + l16;
            bq[j] = *(const bf16x8*)(Bs + row * 32 + (quad ^ ((row >> 1) & 3)) * 8);
        }
#pragma unroll
        for (int i = 0; i < 4; ++i)
#pragma unroll
            for (int j = 0; j < 4; ++j)
                acc[i][j] = __builtin_amdgcn_mfma_f32_16x16x32_bf16(af[i], bq[j], acc[i][j], 0, 0, 0);
        __syncthreads();
    }
#pragma unroll
    for (int i = 0; i < 4; ++i)
#pragma unroll
        for (int j = 0; j < 4; ++j)
#pragma unroll
            for (int r = 0; r < 4; ++r) {
                int row = brow + wy * 64 + i * 16 + quad * 4 + r;
                int col = bcol + wx * 64 + j * 16 + l16;
                C[(size_t)row * N + col] = acc[i][j][r];
            }
}

// ---------------- flash attention v12: 4 blocks/CU + MFMA l-sum -------------
// (unchanged — no longer the top dispatch)
__constant__ unsigned char c_sched[24] = {
    28, 61, 57, 58, 24, 53, 49, 20,
    62, 54, 50, 41, 42, 16, 45, 46,
     0,  4,  8, 12, 33, 37, 34, 38};

__global__ __launch_bounds__(256, 4) void attn_kernel(const bf16* __restrict__ qb,
                                                      const bf16* __restrict__ kb,
                                                      const bf16* __restrict__ vt,
                                                      float* __restrict__ Oacc,
                                                      float* __restrict__ Lacc,
                                                      bf16* __restrict__ conc) {
    __shared__ bf16 Ks[2][64 * 64];                // 2 x 8 KB
    __shared__ bf16 Vs[2][64 * 64];                // 2 x 8 KB
    __shared__ bf16 Pl[4][16 * 64];                // 8 KB (per-wave, shared g0/g1)
    const int bh = blockIdx.y;
    const int b = bh >> 4, h = bh & 15;

    const int e    = c_sched[blockIdx.x];
    const int tile = e >> 2, mode = e & 3;
    const int it0  = (mode == 2) ? tile + 1 : 0;
    const int it1  = (mode == 1) ? tile : 2 * tile + 1;
    const bool partial = (mode != 0);
    const int qbase = tile << 7;                   // 128 queries per tile

    const int tid = threadIdx.x;
    const int lane = tid & 63, wave = tid >> 6;
    const int l16 = lane & 15, quad = lane >> 4;
    const int qr0 = qbase + wave * 16;             // group0 query rows
    const int qr1 = qr0 + 64;                      // group1 query rows

    const bf16* Qp = qb + (size_t)bh * T_SEQ * DK;
    const bf16* Kp = kb + (size_t)bh * T_SEQ * DK;
    const bf16* Vp = vt + (size_t)bh * DK * T_SEQ;
    char* Pw = (char*)&Pl[wave][0];

    // ones B-fragment for the l row-sum MFMA
    const short one_bits = 0x3F80;
    const bf16x8 ones = {one_bits, one_bits, one_bits, one_bits,
                         one_bits, one_bits, one_bits, one_bits};

    // Q as B-operand: n = query = l16, k = dk = quad*8+j (+32 per kstep)
    bf16x8 qf[2][2];
#pragma unroll
    for (int s = 0; s < 2; ++s) {
        qf[0][s] = *(const bf16x8*)(Qp + (size_t)(qr0 + l16) * DK + s * 32 + quad * 8);
        qf[1][s] = *(const bf16x8*)(Qp + (size_t)(qr1 + l16) * DK + s * 32 + quad * 8);
    }

    // stage row-major 64x64 tile with XOR-swizzled 16B col-blocks
    auto stage = [&](int bb, int k0) {
        int j = tid;
#pragma unroll
        for (int i = 0; i < 2; ++i, j += 256) {
            int row = j >> 3, cbl = (j & 7) ^ ((j >> 3) & 7);
            load_lds16(Kp + (size_t)(k0 + row) * DK + cbl * 8, (char*)Ks[bb] + j * 16);
        }
        j = tid;
#pragma unroll
        for (int i = 0; i < 2; ++i, j += 256) {
            int row = j >> 3, cbl = (j & 7) ^ ((j >> 3) & 7);
            load_lds16(Vp + (size_t)row * T_SEQ + k0 + cbl * 8, (char*)Vs[bb] + j * 16);
        }
    };

    f32x4 o0[4] = {}, o1[4] = {};
    f32x4 ol0 = {}, ol1 = {};      // l row-sums (same C-rows as o*[j])
    const int sw0 = (quad ^ (l16 & 7)) * 8;
    const int sw1 = ((4 + quad) ^ (l16 & 7)) * 8;
    // P buffer addressing (bytes): row=l16 (128B), XOR-swizzled 16B blocks
    const int pw_wr_base = l16 * 128 + (quad & 1) * 8;   // + swizzled block
    const int pq = quad >> 1;

    int cur = 0;
    stage(0, it0 * 64);
    for (int it = it0; it <= it1; ++it) {
        __syncthreads();                      // drains DMA for cur + syncs waves
        if (it < it1) stage(cur ^ 1, (it + 1) * 64);

        const int k0 = it * 64;
        const bool skip0 = (k0 > qr0 + 15);             // wave-uniform
        const bool diag0 = (k0 + 63 > qr0) && !skip0;
        const bool diag1 = (k0 + 63 > qr1);             // skip1 never happens

        // S^T = K Q^T over 64 keys; kf fragments shared by both groups
        f32x4 s0[4] = {}, s1[4] = {};
        __builtin_amdgcn_s_setprio(1);
#pragma unroll
        for (int nt = 0; nt < 4; ++nt) {
            bf16x8 kf0 = *(const bf16x8*)(Ks[cur] + (nt * 16 + l16) * 64 + sw0);
            bf16x8 kf1 = *(const bf16x8*)(Ks[cur] + (nt * 16 + l16) * 64 + sw1);
            if (!skip0) {
                s0[nt] = __builtin_amdgcn_mfma_f32_16x16x32_bf16(kf0, qf[0][0], s0[nt], 0, 0, 0);
                s0[nt] = __builtin_amdgcn_mfma_f32_16x16x32_bf16(kf1, qf[0][1], s0[nt], 0, 0, 0);
            }
            s1[nt] = __builtin_amdgcn_mfma_f32_16x16x32_bf16(kf0, qf[1][0], s1[nt], 0, 0, 0);
            s1[nt] = __builtin_amdgcn_mfma_f32_16x16x32_bf16(kf1, qf[1][1], s1[nt], 0, 0, 0);
        }
        __builtin_amdgcn_s_setprio(0);

        // ---- group 0: exp -> P buffer -> PV (+ l-sum MFMA) ----
        if (!skip0) {
#pragma unroll
            for (int nt = 0; nt < 4; ++nt) {
                union { bf16 hv[4]; uint2 u; } pk;
#pragma unroll
                for (int r = 0; r < 4; ++r) {
                    float v = s0[nt][r];
                    if (diag0 && (k0 + nt * 16 + quad * 4 + r > qr0 + l16)) v = -30.0f;
                    pk.hv[r] = __float2bfloat16(exp2f(v));
                }
                *(uint2*)(Pw + pw_wr_base + (((nt * 2 + pq) ^ (l16 & 7)) << 4)) = pk.u;
            }
            __builtin_amdgcn_s_setprio(1);
#pragma unroll
            for (int ks = 0; ks < 2; ++ks) {
                bf16x8 pf = *(const bf16x8*)(Pw + l16 * 128 + (((ks * 4 + quad) ^ (l16 & 7)) << 4));
                const int sw = ks ? sw1 : sw0;
                ol0 = __builtin_amdgcn_mfma_f32_16x16x32_bf16(pf, ones, ol0, 0, 0, 0);
#pragma unroll
                for (int j = 0; j < 4; ++j) {
                    bf16x8 vf = *(const bf16x8*)(Vs[cur] + (j * 16 + l16) * 64 + sw);
                    o0[j] = __builtin_amdgcn_mfma_f32_16x16x32_bf16(pf, vf, o0[j], 0, 0, 0);
                }
            }
            __builtin_amdgcn_s_setprio(0);
        }

        // ---- group 1: exp -> P buffer (reused; per-wave DS pipe is in-order,
        // so these writes cannot pass g0's pf reads) -> PV (+ l-sum MFMA) ----
#pragma unroll
        for (int nt = 0; nt < 4; ++nt) {
            union { bf16 hv[4]; uint2 u; } pk;
#pragma unroll
            for (int r = 0; r < 4; ++r) {
                float v = s1[nt][r];
                if (diag1 && (k0 + nt * 16 + quad * 4 + r > qr1 + l16)) v = -30.0f;
                pk.hv[r] = __float2bfloat16(exp2f(v));
            }
            *(uint2*)(Pw + pw_wr_base + (((nt * 2 + pq) ^ (l16 & 7)) << 4)) = pk.u;
        }
        __builtin_amdgcn_s_setprio(1);
#pragma unroll
        for (int ks = 0; ks < 2; ++ks) {
            bf16x8 pf = *(const bf16x8*)(Pw + l16 * 128 + (((ks * 4 + quad) ^ (l16 & 7)) << 4));
            const int sw = ks ? sw1 : sw0;
            ol1 = __builtin_amdgcn_mfma_f32_16x16x32_bf16(pf, ones, ol1, 0, 0, 0);
#pragma unroll
            for (int j = 0; j < 4; ++j) {
                bf16x8 vf = *(const bf16x8*)(Vs[cur] + (j * 16 + l16) * 64 + sw);
                o1[j] = __builtin_amdgcn_mfma_f32_16x16x32_bf16(pf, vf, o1[j], 0, 0, 0);
            }
        }
        __builtin_amdgcn_s_setprio(0);
        cur ^= 1;
    }

    // epilogue: ol*[r] is the full l for query qr + quad*4 + r (no shuffles)
#pragma unroll
    for (int g = 0; g < 2; ++g) {
        const f32x4* op = g ? o1 : o0;
        const f32x4 lv = g ? ol1 : ol0;
        const int qr = g ? qr1 : qr0;
        if (!partial) {
#pragma unroll
            for (int r = 0; r < 4; ++r) {
                float inv_l = 1.0f / lv[r];
                int t = qr + quad * 4 + r;
#pragma unroll
                for (int j = 0; j < 4; ++j)
                    conc[((size_t)b * T_SEQ + t) * DMODEL + h * DK + j * 16 + l16] =
                        __float2bfloat16(op[j][r] * inv_l);
            }
        } else {
#pragma unroll
            for (int r = 0; r < 4; ++r) {
                int q = qr + quad * 4 + r;
                if (l16 == 0)
                    atomicAdd(&Lacc[(size_t)bh * 1024 + q - 1024], lv[r]);
                float* Ob = Oacc + ((size_t)bh * 1024 + q - 1024) * DK;
#pragma unroll
                for (int j = 0; j < 4; ++j)
                    atomicAdd(&Ob[j * 16 + l16], op[j][r]);
            }
        }
    }
}

// ---------------- normalize + concat (only q in [1024, 2048)) ----------------
__global__ void attn_finalize(const float* __restrict__ Oacc, const float* __restrict__ Lacc,
                              bf16* __restrict__ conc) {
    int i4 = blockIdx.x * blockDim.x + threadIdx.x;   // float4 units, 0..512K-1
    if (i4 >= (1 << 19)) return;
    int bhq = i4 >> 4;          // bh*1024 + q1
    int d4  = i4 & 15;
    int bh = bhq >> 10, q1 = bhq & 1023;
    int b = bh >> 4, h = bh & 15;
    int q = 1024 + q1;
    float inv = 1.0f / Lacc[bhq];
    float4 o4 = ((const float4*)Oacc)[i4];
    ushort4 u;
    u.x = __bfloat16_as_ushort(__float2bfloat16(o4.x * inv));
    u.y = __bfloat16_as_ushort(__float2bfloat16(o4.y * inv));
    u.z = __bfloat16_as_ushort(__float2bfloat16(o4.z * inv));
    u.w = __bfloat16_as_ushort(__float2bfloat16(o4.w * inv));
    *(ushort4*)&conc[((size_t)(b * T_SEQ + q)) * DMODEL + h * DK + d4 * 4] = u;
}

extern "C" void kernel_launch(void* const* d_in, const int* in_sizes, int n_in,
                              void* d_out, int out_size, void* d_ws, size_t ws_size,
                              hipStream_t stream) {
    const float* x  = (const float*)d_in[0];
    const float* wq = (const float*)d_in[1];
    const float* wk = (const float*)d_in[2];
    const float* wv = (const float*)d_in[3];
    const float* wo = (const float*)d_in[4];
    float* out = (float*)d_out;

    char* ws = (char*)d_ws;
    bf16* xb    = (bf16*)(ws);                      // 8 MiB  (4096x1024)
    bf16* wqkvb = (bf16*)(ws + (8ull << 20));       // 6 MiB  (3072x1024)
    bf16* wob   = (bf16*)(ws + (14ull << 20));      // 2 MiB  (1024x1024)
    bf16* qb    = (bf16*)(ws + (40ull << 20));      // 8 MiB
    bf16* kb    = (bf16*)(ws + (48ull << 20));      // 8 MiB
    bf16* vt    = (bf16*)(ws + (56ull << 20));      // 8 MiB
    bf16* conc  = (bf16*)(ws + (16ull << 20));      // 8 MiB
    float* Oacc = (float*)(ws + (24ull << 20));     // 8 MiB
    float* Lacc = (float*)(ws + (32ull << 20));     // 128 KiB
    float2* rtab = (float2*)(ws + (34ull << 20));   // 512 KiB (2048x32 cos/sin)

    rope_table_k<<<256, 256, 0, stream>>>(rtab);
    cvt_all<<<8192, 256, 0, stream>>>(x, wq, wk, wv, wo, xb, wqkvb, wob);
    gemm_qkv_rope<<<dim3(24, 32), 256, 0, stream>>>(xb, wqkvb, rtab, qb, kb, vt);

    hipMemsetAsync(Oacc, 0, (8ull << 20) + 32 * 1024 * sizeof(float), stream);
    attn_kernel<<<dim3(24, 32), 256, 0, stream>>>(qb, kb, vt, Oacc, Lacc, conc);
    attn_finalize<<<2048, 256, 0, stream>>>(Oacc, Lacc, conc);

    gemm_bt<<<dim3(8, 32), 256, 0, stream>>>(conc, wob, out, 4096, 1024, 1024);
}

// Round 6
// 207.179 us; speedup vs baseline: 1.1736x; 1.1736x over previous
//
#include <hip/hip_runtime.h>
#include <hip/hip_bf16.h>

typedef __hip_bfloat16 bf16;
typedef __attribute__((ext_vector_type(8))) short bf16x8;
typedef __attribute__((ext_vector_type(4))) float f32x4;

#define T_SEQ 2048
#define NHEADS 16
#define DK 64
#define DMODEL 1024

__device__ inline void load_lds16(const void* g, void* l) {
    __builtin_amdgcn_global_load_lds((const __attribute__((address_space(1))) void*)g,
                                     (__attribute__((address_space(3))) void*)l, 16, 0, 0);
}

// ---------------- fp32 -> bf16 convert: x + all four weights, one launch ----
__global__ void cvt_all(const float* __restrict__ x,  const float* __restrict__ wq,
                        const float* __restrict__ wk, const float* __restrict__ wv,
                        const float* __restrict__ wo, bf16* __restrict__ xb,
                        bf16* __restrict__ wqkvb, bf16* __restrict__ wob) {
    int i = blockIdx.x * blockDim.x + threadIdx.x;   // 0 .. 2M-1 (float4 units)
    const float* src; bf16* dst; int off;
    if (i < (1 << 20)) { src = x; dst = xb; off = i; }
    else {
        int j = i - (1 << 20);
        int seg = j >> 18; off = j & ((1 << 18) - 1);
        src = (seg == 0) ? wq : (seg == 1) ? wk : (seg == 2) ? wv : wo;
        dst = (seg < 3) ? (wqkvb + ((size_t)seg << 20)) : wob;
    }
    float4 f = ((const float4*)src)[off];
    ushort4 o;
    o.x = __bfloat16_as_ushort(__float2bfloat16(f.x));
    o.y = __bfloat16_as_ushort(__float2bfloat16(f.y));
    o.z = __bfloat16_as_ushort(__float2bfloat16(f.z));
    o.w = __bfloat16_as_ushort(__float2bfloat16(f.w));
    ((ushort4*)dst)[off] = o;
}

// ---------------- GEMM1: qkv = x * Wqkv^T, fused RoPE + head split ----------
// v15 = round-3 base (single-buffer loop, sincos epilogue, VGPR 104) + LDS
// XOR swizzle ONLY (v14 PMC-verified: bank conflicts 3.15M -> 0; v14's other
// two pieces — table epilogue, transposed-V branch — blew VGPR to 160 and
// are reverted). Stage: linear LDS dest + pre-swizzled global source block
// cc = (j&3) ^ ((row>>1)&3). Read: block = quad ^ ((l16>>1)&3) (the row-XOR
// term reduces to l16 bits -> loop-invariant, ~4 extra VGPRs).
// C rows = b*2048+t, cols = e in [0,3072): seg 0=q (rope'd, PRE-SCALED by
// log2(e)/sqrt(dk)), 1=k (rope'd) -> qb/kb [bh][t][dk], seg 2=v (transposed
// -> vt [bh][dk][t]). Rope pair (2i,2i+1) lives in adjacent lanes.
__global__ __launch_bounds__(256) void gemm_qkv_rope(const bf16* __restrict__ A,
                                                     const bf16* __restrict__ B,
                                                     bf16* __restrict__ qb,
                                                     bf16* __restrict__ kb,
                                                     bf16* __restrict__ vt) {
    const int K = 1024;
    __shared__ bf16 As[128 * 32];
    __shared__ bf16 Bs[128 * 32];
    const int tid  = threadIdx.x;
    const int lane = tid & 63;
    const int wave = tid >> 6;
    const int l16  = lane & 15;
    const int quad = lane >> 4;
    const int wy = wave >> 1, wx = wave & 1;
    const int brow = blockIdx.y * 128;
    const int bcol = blockIdx.x * 128;
    const int swz  = (l16 >> 1) & 3;               // read-side XOR (invariant)

    f32x4 acc[4][4] = {};

    for (int k0 = 0; k0 < K; k0 += 32) {
#pragma unroll
        for (int i = 0; i < 2; ++i) {
            int j   = tid + 256 * i;
            int row = j >> 2;
            int cc  = (j & 3) ^ ((row >> 1) & 3);  // pre-swizzled source block
            load_lds16(A + (size_t)(brow + row) * K + k0 + cc * 8, (char*)As + j * 16);
            load_lds16(B + (size_t)(bcol + row) * K + k0 + cc * 8, (char*)Bs + j * 16);
        }
        __syncthreads();
        bf16x8 af[4], bq[4];
#pragma unroll
        for (int i = 0; i < 4; ++i)
            af[i] = *(const bf16x8*)(As + (wy * 64 + i * 16 + l16) * 32 + (quad ^ swz) * 8);
#pragma unroll
        for (int j = 0; j < 4; ++j)
            bq[j] = *(const bf16x8*)(Bs + (wx * 64 + j * 16 + l16) * 32 + (quad ^ swz) * 8);
#pragma unroll
        for (int i = 0; i < 4; ++i)
#pragma unroll
            for (int j = 0; j < 4; ++j)
                acc[i][j] = __builtin_amdgcn_mfma_f32_16x16x32_bf16(af[i], bq[j], acc[i][j], 0, 0, 0);
        __syncthreads();
    }
    const int seg = bcol >> 10;                       // uniform per block
    const int hh  = ((bcol & 1023) >> 6) + wx;        // head index
    if (seg < 2) {
        bf16* dst = seg ? kb : qb;
        // q pre-scaled so attn computes p = exp2(q'.k) directly
        const float osc = seg ? 1.0f : 0.18033688011112042f;  // log2(e)/8
#pragma unroll
        for (int j = 0; j < 4; ++j) {
            const int d = j * 16 + l16;               // dk within head
            const float inv = exp2f(-0.31143075889f * (float)(d >> 1));  // 1000^(-i/32)
#pragma unroll
            for (int i = 0; i < 4; ++i)
#pragma unroll
                for (int r = 0; r < 4; ++r) {
                    int row = brow + wy * 64 + i * 16 + quad * 4 + r;
                    int t = row & (T_SEQ - 1), bi = row >> 11;
                    float s, c;
                    __sincosf((float)t * inv, &s, &c);
                    float v = acc[i][j][r];
                    float p = __shfl_xor(v, 1);
                    float res = (l16 & 1) ? fmaf(p, s, v * c) : fmaf(-p, s, v * c);
                    dst[((size_t)(bi * NHEADS + hh) * T_SEQ + t) * DK + d] =
                        __float2bfloat16(res * osc);
                }
        }
    } else {
#pragma unroll
        for (int j = 0; j < 4; ++j) {
            const int d = j * 16 + l16;
#pragma unroll
            for (int i = 0; i < 4; ++i)
#pragma unroll
                for (int r = 0; r < 4; ++r) {
                    int row = brow + wy * 64 + i * 16 + quad * 4 + r;
                    int t = row & (T_SEQ - 1), bi = row >> 11;
                    vt[((size_t)(bi * NHEADS + hh) * DK + d) * T_SEQ + t] =
                        __float2bfloat16(acc[i][j][r]);
                }
        }
    }
}

// ---------------- GEMM: C[M,N] = A[M,K] * B[N,K]^T (fp32 out) ----------------
// v15: round-3 single-buffer loop + LDS XOR swizzle (same scheme as gemm1).
__global__ __launch_bounds__(256) void gemm_bt(const bf16* __restrict__ A,
                                               const bf16* __restrict__ B,
                                               float* __restrict__ C,
                                               int M, int N, int K) {
    __shared__ bf16 As[128 * 32];
    __shared__ bf16 Bs[128 * 32];
    const int tid  = threadIdx.x;
    const int lane = tid & 63;
    const int wave = tid >> 6;
    const int l16  = lane & 15;
    const int quad = lane >> 4;
    const int wy = wave >> 1, wx = wave & 1;
    const int brow = blockIdx.y * 128;
    const int bcol = blockIdx.x * 128;
    const int swz  = (l16 >> 1) & 3;

    f32x4 acc[4][4] = {};

    for (int k0 = 0; k0 < K; k0 += 32) {
#pragma unroll
        for (int i = 0; i < 2; ++i) {
            int j   = tid + 256 * i;
            int row = j >> 2;
            int cc  = (j & 3) ^ ((row >> 1) & 3);
            load_lds16(A + (size_t)(brow + row) * K + k0 + cc * 8, (char*)As + j * 16);
            load_lds16(B + (size_t)(bcol + row) * K + k0 + cc * 8, (char*)Bs + j * 16);
        }
        __syncthreads();
        bf16x8 af[4], bq[4];
#pragma unroll
        for (int i = 0; i < 4; ++i)
            af[i] = *(const bf16x8*)(As + (wy * 64 + i * 16 + l16) * 32 + (quad ^ swz) * 8);
#pragma unroll
        for (int j = 0; j < 4; ++j)
            bq[j] = *(const bf16x8*)(Bs + (wx * 64 + j * 16 + l16) * 32 + (quad ^ swz) * 8);
#pragma unroll
        for (int i = 0; i < 4; ++i)
#pragma unroll
            for (int j = 0; j < 4; ++j)
                acc[i][j] = __builtin_amdgcn_mfma_f32_16x16x32_bf16(af[i], bq[j], acc[i][j], 0, 0, 0);
        __syncthreads();
    }
#pragma unroll
    for (int i = 0; i < 4; ++i)
#pragma unroll
        for (int j = 0; j < 4; ++j)
#pragma unroll
            for (int r = 0; r < 4; ++r) {
                int row = brow + wy * 64 + i * 16 + quad * 4 + r;
                int col = bcol + wx * 64 + j * 16 + l16;
                C[(size_t)row * N + col] = acc[i][j][r];
            }
}

// ---------------- flash attention v12: 4 blocks/CU + MFMA l-sum -------------
// (unchanged — no longer the top dispatch)
__constant__ unsigned char c_sched[24] = {
    28, 61, 57, 58, 24, 53, 49, 20,
    62, 54, 50, 41, 42, 16, 45, 46,
     0,  4,  8, 12, 33, 37, 34, 38};

__global__ __launch_bounds__(256, 4) void attn_kernel(const bf16* __restrict__ qb,
                                                      const bf16* __restrict__ kb,
                                                      const bf16* __restrict__ vt,
                                                      float* __restrict__ Oacc,
                                                      float* __restrict__ Lacc,
                                                      bf16* __restrict__ conc) {
    __shared__ bf16 Ks[2][64 * 64];                // 2 x 8 KB
    __shared__ bf16 Vs[2][64 * 64];                // 2 x 8 KB
    __shared__ bf16 Pl[4][16 * 64];                // 8 KB (per-wave, shared g0/g1)
    const int bh = blockIdx.y;
    const int b = bh >> 4, h = bh & 15;

    const int e    = c_sched[blockIdx.x];
    const int tile = e >> 2, mode = e & 3;
    const int it0  = (mode == 2) ? tile + 1 : 0;
    const int it1  = (mode == 1) ? tile : 2 * tile + 1;
    const bool partial = (mode != 0);
    const int qbase = tile << 7;                   // 128 queries per tile

    const int tid = threadIdx.x;
    const int lane = tid & 63, wave = tid >> 6;
    const int l16 = lane & 15, quad = lane >> 4;
    const int qr0 = qbase + wave * 16;             // group0 query rows
    const int qr1 = qr0 + 64;                      // group1 query rows

    const bf16* Qp = qb + (size_t)bh * T_SEQ * DK;
    const bf16* Kp = kb + (size_t)bh * T_SEQ * DK;
    const bf16* Vp = vt + (size_t)bh * DK * T_SEQ;
    char* Pw = (char*)&Pl[wave][0];

    // ones B-fragment for the l row-sum MFMA
    const short one_bits = 0x3F80;
    const bf16x8 ones = {one_bits, one_bits, one_bits, one_bits,
                         one_bits, one_bits, one_bits, one_bits};

    // Q as B-operand: n = query = l16, k = dk = quad*8+j (+32 per kstep)
    bf16x8 qf[2][2];
#pragma unroll
    for (int s = 0; s < 2; ++s) {
        qf[0][s] = *(const bf16x8*)(Qp + (size_t)(qr0 + l16) * DK + s * 32 + quad * 8);
        qf[1][s] = *(const bf16x8*)(Qp + (size_t)(qr1 + l16) * DK + s * 32 + quad * 8);
    }

    // stage row-major 64x64 tile with XOR-swizzled 16B col-blocks
    auto stage = [&](int bb, int k0) {
        int j = tid;
#pragma unroll
        for (int i = 0; i < 2; ++i, j += 256) {
            int row = j >> 3, cbl = (j & 7) ^ ((j >> 3) & 7);
            load_lds16(Kp + (size_t)(k0 + row) * DK + cbl * 8, (char*)Ks[bb] + j * 16);
        }
        j = tid;
#pragma unroll
        for (int i = 0; i < 2; ++i, j += 256) {
            int row = j >> 3, cbl = (j & 7) ^ ((j >> 3) & 7);
            load_lds16(Vp + (size_t)row * T_SEQ + k0 + cbl * 8, (char*)Vs[bb] + j * 16);
        }
    };

    f32x4 o0[4] = {}, o1[4] = {};
    f32x4 ol0 = {}, ol1 = {};      // l row-sums (same C-rows as o*[j])
    const int sw0 = (quad ^ (l16 & 7)) * 8;
    const int sw1 = ((4 + quad) ^ (l16 & 7)) * 8;
    // P buffer addressing (bytes): row=l16 (128B), XOR-swizzled 16B blocks
    const int pw_wr_base = l16 * 128 + (quad & 1) * 8;   // + swizzled block
    const int pq = quad >> 1;

    int cur = 0;
    stage(0, it0 * 64);
    for (int it = it0; it <= it1; ++it) {
        __syncthreads();                      // drains DMA for cur + syncs waves
        if (it < it1) stage(cur ^ 1, (it + 1) * 64);

        const int k0 = it * 64;
        const bool skip0 = (k0 > qr0 + 15);             // wave-uniform
        const bool diag0 = (k0 + 63 > qr0) && !skip0;
        const bool diag1 = (k0 + 63 > qr1);             // skip1 never happens

        // S^T = K Q^T over 64 keys; kf fragments shared by both groups
        f32x4 s0[4] = {}, s1[4] = {};
        __builtin_amdgcn_s_setprio(1);
#pragma unroll
        for (int nt = 0; nt < 4; ++nt) {
            bf16x8 kf0 = *(const bf16x8*)(Ks[cur] + (nt * 16 + l16) * 64 + sw0);
            bf16x8 kf1 = *(const bf16x8*)(Ks[cur] + (nt * 16 + l16) * 64 + sw1);
            if (!skip0) {
                s0[nt] = __builtin_amdgcn_mfma_f32_16x16x32_bf16(kf0, qf[0][0], s0[nt], 0, 0, 0);
                s0[nt] = __builtin_amdgcn_mfma_f32_16x16x32_bf16(kf1, qf[0][1], s0[nt], 0, 0, 0);
            }
            s1[nt] = __builtin_amdgcn_mfma_f32_16x16x32_bf16(kf0, qf[1][0], s1[nt], 0, 0, 0);
            s1[nt] = __builtin_amdgcn_mfma_f32_16x16x32_bf16(kf1, qf[1][1], s1[nt], 0, 0, 0);
        }
        __builtin_amdgcn_s_setprio(0);

        // ---- group 0: exp -> P buffer -> PV (+ l-sum MFMA) ----
        if (!skip0) {
#pragma unroll
            for (int nt = 0; nt < 4; ++nt) {
                union { bf16 hv[4]; uint2 u; } pk;
#pragma unroll
                for (int r = 0; r < 4; ++r) {
                    float v = s0[nt][r];
                    if (diag0 && (k0 + nt * 16 + quad * 4 + r > qr0 + l16)) v = -30.0f;
                    pk.hv[r] = __float2bfloat16(exp2f(v));
                }
                *(uint2*)(Pw + pw_wr_base + (((nt * 2 + pq) ^ (l16 & 7)) << 4)) = pk.u;
            }
            __builtin_amdgcn_s_setprio(1);
#pragma unroll
            for (int ks = 0; ks < 2; ++ks) {
                bf16x8 pf = *(const bf16x8*)(Pw + l16 * 128 + (((ks * 4 + quad) ^ (l16 & 7)) << 4));
                const int sw = ks ? sw1 : sw0;
                ol0 = __builtin_amdgcn_mfma_f32_16x16x32_bf16(pf, ones, ol0, 0, 0, 0);
#pragma unroll
                for (int j = 0; j < 4; ++j) {
                    bf16x8 vf = *(const bf16x8*)(Vs[cur] + (j * 16 + l16) * 64 + sw);
                    o0[j] = __builtin_amdgcn_mfma_f32_16x16x32_bf16(pf, vf, o0[j], 0, 0, 0);
                }
            }
            __builtin_amdgcn_s_setprio(0);
        }

        // ---- group 1: exp -> P buffer (reused; per-wave DS pipe is in-order,
        // so these writes cannot pass g0's pf reads) -> PV (+ l-sum MFMA) ----
#pragma unroll
        for (int nt = 0; nt < 4; ++nt) {
            union { bf16 hv[4]; uint2 u; } pk;
#pragma unroll
            for (int r = 0; r < 4; ++r) {
                float v = s1[nt][r];
                if (diag1 && (k0 + nt * 16 + quad * 4 + r > qr1 + l16)) v = -30.0f;
                pk.hv[r] = __float2bfloat16(exp2f(v));
            }
            *(uint2*)(Pw + pw_wr_base + (((nt * 2 + pq) ^ (l16 & 7)) << 4)) = pk.u;
        }
        __builtin_amdgcn_s_setprio(1);
#pragma unroll
        for (int ks = 0; ks < 2; ++ks) {
            bf16x8 pf = *(const bf16x8*)(Pw + l16 * 128 + (((ks * 4 + quad) ^ (l16 & 7)) << 4));
            const int sw = ks ? sw1 : sw0;
            ol1 = __builtin_amdgcn_mfma_f32_16x16x32_bf16(pf, ones, ol1, 0, 0, 0);
#pragma unroll
            for (int j = 0; j < 4; ++j) {
                bf16x8 vf = *(const bf16x8*)(Vs[cur] + (j * 16 + l16) * 64 + sw);
                o1[j] = __builtin_amdgcn_mfma_f32_16x16x32_bf16(pf, vf, o1[j], 0, 0, 0);
            }
        }
        __builtin_amdgcn_s_setprio(0);
        cur ^= 1;
    }

    // epilogue: ol*[r] is the full l for query qr + quad*4 + r (no shuffles)
#pragma unroll
    for (int g = 0; g < 2; ++g) {
        const f32x4* op = g ? o1 : o0;
        const f32x4 lv = g ? ol1 : ol0;
        const int qr = g ? qr1 : qr0;
        if (!partial) {
#pragma unroll
            for (int r = 0; r < 4; ++r) {
                float inv_l = 1.0f / lv[r];
                int t = qr + quad * 4 + r;
#pragma unroll
                for (int j = 0; j < 4; ++j)
                    conc[((size_t)b * T_SEQ + t) * DMODEL + h * DK + j * 16 + l16] =
                        __float2bfloat16(op[j][r] * inv_l);
            }
        } else {
#pragma unroll
            for (int r = 0; r < 4; ++r) {
                int q = qr + quad * 4 + r;
                if (l16 == 0)
                    atomicAdd(&Lacc[(size_t)bh * 1024 + q - 1024], lv[r]);
                float* Ob = Oacc + ((size_t)bh * 1024 + q - 1024) * DK;
#pragma unroll
                for (int j = 0; j < 4; ++j)
                    atomicAdd(&Ob[j * 16 + l16], op[j][r]);
            }
        }
    }
}

// ---------------- normalize + concat (only q in [1024, 2048)) ----------------
__global__ void attn_finalize(const float* __restrict__ Oacc, const float* __restrict__ Lacc,
                              bf16* __restrict__ conc) {
    int i4 = blockIdx.x * blockDim.x + threadIdx.x;   // float4 units, 0..512K-1
    if (i4 >= (1 << 19)) return;
    int bhq = i4 >> 4;          // bh*1024 + q1
    int d4  = i4 & 15;
    int bh = bhq >> 10, q1 = bhq & 1023;
    int b = bh >> 4, h = bh & 15;
    int q = 1024 + q1;
    float inv = 1.0f / Lacc[bhq];
    float4 o4 = ((const float4*)Oacc)[i4];
    ushort4 u;
    u.x = __bfloat16_as_ushort(__float2bfloat16(o4.x * inv));
    u.y = __bfloat16_as_ushort(__float2bfloat16(o4.y * inv));
    u.z = __bfloat16_as_ushort(__float2bfloat16(o4.z * inv));
    u.w = __bfloat16_as_ushort(__float2bfloat16(o4.w * inv));
    *(ushort4*)&conc[((size_t)(b * T_SEQ + q)) * DMODEL + h * DK + d4 * 4] = u;
}

extern "C" void kernel_launch(void* const* d_in, const int* in_sizes, int n_in,
                              void* d_out, int out_size, void* d_ws, size_t ws_size,
                              hipStream_t stream) {
    const float* x  = (const float*)d_in[0];
    const float* wq = (const float*)d_in[1];
    const float* wk = (const float*)d_in[2];
    const float* wv = (const float*)d_in[3];
    const float* wo = (const float*)d_in[4];
    float* out = (float*)d_out;

    char* ws = (char*)d_ws;
    bf16* xb    = (bf16*)(ws);                      // 8 MiB  (4096x1024)
    bf16* wqkvb = (bf16*)(ws + (8ull << 20));       // 6 MiB  (3072x1024)
    bf16* wob   = (bf16*)(ws + (14ull << 20));      // 2 MiB  (1024x1024)
    bf16* qb    = (bf16*)(ws + (40ull << 20));      // 8 MiB
    bf16* kb    = (bf16*)(ws + (48ull << 20));      // 8 MiB
    bf16* vt    = (bf16*)(ws + (56ull << 20));      // 8 MiB
    bf16* conc  = (bf16*)(ws + (16ull << 20));      // 8 MiB
    float* Oacc = (float*)(ws + (24ull << 20));     // 8 MiB
    float* Lacc = (float*)(ws + (32ull << 20));     // 128 KiB

    cvt_all<<<8192, 256, 0, stream>>>(x, wq, wk, wv, wo, xb, wqkvb, wob);
    gemm_qkv_rope<<<dim3(24, 32), 256, 0, stream>>>(xb, wqkvb, qb, kb, vt);

    hipMemsetAsync(Oacc, 0, (8ull << 20) + 32 * 1024 * sizeof(float), stream);
    attn_kernel<<<dim3(24, 32), 256, 0, stream>>>(qb, kb, vt, Oacc, Lacc, conc);
    attn_finalize<<<2048, 256, 0, stream>>>(Oacc, Lacc, conc);

    gemm_bt<<<dim3(8, 32), 256, 0, stream>>>(conc, wob, out, 4096, 1024, 1024);
}

// Round 7
// 182.743 us; speedup vs baseline: 1.3306x; 1.1337x over previous
//
#include <hip/hip_runtime.h>
#include <hip/hip_bf16.h>

typedef __hip_bfloat16 bf16;
typedef __attribute__((ext_vector_type(8))) short bf16x8;
typedef __attribute__((ext_vector_type(4))) float f32x4;

#define T_SEQ 2048
#define NHEADS 16
#define DK 64
#define DMODEL 1024

__device__ inline void load_lds16(const void* g, void* l) {
    __builtin_amdgcn_global_load_lds((const __attribute__((address_space(1))) void*)g,
                                     (__attribute__((address_space(3))) void*)l, 16, 0, 0);
}

// ---------------- fp32 -> bf16 convert: x + all four weights, one launch ----
__global__ void cvt_all(const float* __restrict__ x,  const float* __restrict__ wq,
                        const float* __restrict__ wk, const float* __restrict__ wv,
                        const float* __restrict__ wo, bf16* __restrict__ xb,
                        bf16* __restrict__ wqkvb, bf16* __restrict__ wob) {
    int i = blockIdx.x * blockDim.x + threadIdx.x;   // 0 .. 2M-1 (float4 units)
    const float* src; bf16* dst; int off;
    if (i < (1 << 20)) { src = x; dst = xb; off = i; }
    else {
        int j = i - (1 << 20);
        int seg = j >> 18; off = j & ((1 << 18) - 1);
        src = (seg == 0) ? wq : (seg == 1) ? wk : (seg == 2) ? wv : wo;
        dst = (seg < 3) ? (wqkvb + ((size_t)seg << 20)) : wob;
    }
    float4 f = ((const float4*)src)[off];
    ushort4 o;
    o.x = __bfloat16_as_ushort(__float2bfloat16(f.x));
    o.y = __bfloat16_as_ushort(__float2bfloat16(f.y));
    o.z = __bfloat16_as_ushort(__float2bfloat16(f.z));
    o.w = __bfloat16_as_ushort(__float2bfloat16(f.w));
    ((ushort4*)dst)[off] = o;
}

// ---------------- GEMM1: qkv = x * Wqkv^T, fused RoPE + head split ----------
// v16 = v15 (2-barrier template, swizzled LDS, sincos epilogue) with BK 32->64:
// halves the barrier-drain events (32 -> 16 iters), doubles MFMA per staged
// tile. 128x64 tile at 128B row stride needs the attn-style blk^(row&7)
// swizzle (8 16B-blocks/row, phase-conflict-free; v15's 4-block scheme only
// covers stride-64B). LDS 16->32 KB. launch_bounds(256,4) caps VGPR at 128
// (v14 lesson: epilogue batching can blow regs; fragments scoped per k-half).
// C rows = b*2048+t, cols = e in [0,3072): seg 0=q (rope'd, PRE-SCALED by
// log2(e)/sqrt(dk)), 1=k (rope'd) -> qb/kb [bh][t][dk], seg 2=v (transposed
// -> vt [bh][dk][t]). Rope pair (2i,2i+1) lives in adjacent lanes.
__global__ __launch_bounds__(256, 4) void gemm_qkv_rope(const bf16* __restrict__ A,
                                                        const bf16* __restrict__ B,
                                                        bf16* __restrict__ qb,
                                                        bf16* __restrict__ kb,
                                                        bf16* __restrict__ vt) {
    const int K = 1024;
    __shared__ bf16 As[128 * 64];
    __shared__ bf16 Bs[128 * 64];
    const int tid  = threadIdx.x;
    const int lane = tid & 63;
    const int wave = tid >> 6;
    const int l16  = lane & 15;
    const int quad = lane >> 4;
    const int wy = wave >> 1, wx = wave & 1;
    const int brow = blockIdx.y * 128;
    const int bcol = blockIdx.x * 128;
    // fragment read offsets (elements), attn-proven swizzle: blk ^ (l16&7)
    const int sw0 = (quad ^ (l16 & 7)) * 8;
    const int sw1 = ((4 + quad) ^ (l16 & 7)) * 8;

    f32x4 acc[4][4] = {};

    for (int k0 = 0; k0 < K; k0 += 64) {
#pragma unroll
        for (int i = 0; i < 4; ++i) {
            int j   = tid + 256 * i;                  // 0..1023
            int row = j >> 3;
            int blk = (j & 7) ^ (row & 7);            // pre-swizzled source blk
            load_lds16(A + (size_t)(brow + row) * K + k0 + blk * 8, (char*)As + j * 16);
            load_lds16(B + (size_t)(bcol + row) * K + k0 + blk * 8, (char*)Bs + j * 16);
        }
        __syncthreads();
#pragma unroll
        for (int ks = 0; ks < 2; ++ks) {
            const int sw = ks ? sw1 : sw0;
            bf16x8 af[4], bq[4];
#pragma unroll
            for (int i = 0; i < 4; ++i)
                af[i] = *(const bf16x8*)(As + (wy * 64 + i * 16 + l16) * 64 + sw);
#pragma unroll
            for (int j = 0; j < 4; ++j)
                bq[j] = *(const bf16x8*)(Bs + (wx * 64 + j * 16 + l16) * 64 + sw);
#pragma unroll
            for (int i = 0; i < 4; ++i)
#pragma unroll
                for (int j = 0; j < 4; ++j)
                    acc[i][j] = __builtin_amdgcn_mfma_f32_16x16x32_bf16(af[i], bq[j], acc[i][j], 0, 0, 0);
        }
        __syncthreads();
    }
    const int seg = bcol >> 10;                       // uniform per block
    const int hh  = ((bcol & 1023) >> 6) + wx;        // head index
    if (seg < 2) {
        bf16* dst = seg ? kb : qb;
        // q pre-scaled so attn computes p = exp2(q'.k) directly
        const float osc = seg ? 1.0f : 0.18033688011112042f;  // log2(e)/8
#pragma unroll
        for (int j = 0; j < 4; ++j) {
            const int d = j * 16 + l16;               // dk within head
            const float inv = exp2f(-0.31143075889f * (float)(d >> 1));  // 1000^(-i/32)
#pragma unroll
            for (int i = 0; i < 4; ++i)
#pragma unroll
                for (int r = 0; r < 4; ++r) {
                    int row = brow + wy * 64 + i * 16 + quad * 4 + r;
                    int t = row & (T_SEQ - 1), bi = row >> 11;
                    float s, c;
                    __sincosf((float)t * inv, &s, &c);
                    float v = acc[i][j][r];
                    float p = __shfl_xor(v, 1);
                    float res = (l16 & 1) ? fmaf(p, s, v * c) : fmaf(-p, s, v * c);
                    dst[((size_t)(bi * NHEADS + hh) * T_SEQ + t) * DK + d] =
                        __float2bfloat16(res * osc);
                }
        }
    } else {
#pragma unroll
        for (int j = 0; j < 4; ++j) {
            const int d = j * 16 + l16;
#pragma unroll
            for (int i = 0; i < 4; ++i)
#pragma unroll
                for (int r = 0; r < 4; ++r) {
                    int row = brow + wy * 64 + i * 16 + quad * 4 + r;
                    int t = row & (T_SEQ - 1), bi = row >> 11;
                    vt[((size_t)(bi * NHEADS + hh) * DK + d) * T_SEQ + t] =
                        __float2bfloat16(acc[i][j][r]);
                }
        }
    }
}

// ---------------- GEMM: C[M,N] = A[M,K] * B[N,K]^T (fp32 out) ----------------
// v16: same BK=64 + blk^(row&7) swizzle as gemm_qkv_rope.
__global__ __launch_bounds__(256, 4) void gemm_bt(const bf16* __restrict__ A,
                                                  const bf16* __restrict__ B,
                                                  float* __restrict__ C,
                                                  int M, int N, int K) {
    __shared__ bf16 As[128 * 64];
    __shared__ bf16 Bs[128 * 64];
    const int tid  = threadIdx.x;
    const int lane = tid & 63;
    const int wave = tid >> 6;
    const int l16  = lane & 15;
    const int quad = lane >> 4;
    const int wy = wave >> 1, wx = wave & 1;
    const int brow = blockIdx.y * 128;
    const int bcol = blockIdx.x * 128;
    const int sw0 = (quad ^ (l16 & 7)) * 8;
    const int sw1 = ((4 + quad) ^ (l16 & 7)) * 8;

    f32x4 acc[4][4] = {};

    for (int k0 = 0; k0 < K; k0 += 64) {
#pragma unroll
        for (int i = 0; i < 4; ++i) {
            int j   = tid + 256 * i;
            int row = j >> 3;
            int blk = (j & 7) ^ (row & 7);
            load_lds16(A + (size_t)(brow + row) * K + k0 + blk * 8, (char*)As + j * 16);
            load_lds16(B + (size_t)(bcol + row) * K + k0 + blk * 8, (char*)Bs + j * 16);
        }
        __syncthreads();
#pragma unroll
        for (int ks = 0; ks < 2; ++ks) {
            const int sw = ks ? sw1 : sw0;
            bf16x8 af[4], bq[4];
#pragma unroll
            for (int i = 0; i < 4; ++i)
                af[i] = *(const bf16x8*)(As + (wy * 64 + i * 16 + l16) * 64 + sw);
#pragma unroll
            for (int j = 0; j < 4; ++j)
                bq[j] = *(const bf16x8*)(Bs + (wx * 64 + j * 16 + l16) * 64 + sw);
#pragma unroll
            for (int i = 0; i < 4; ++i)
#pragma unroll
                for (int j = 0; j < 4; ++j)
                    acc[i][j] = __builtin_amdgcn_mfma_f32_16x16x32_bf16(af[i], bq[j], acc[i][j], 0, 0, 0);
        }
        __syncthreads();
    }
#pragma unroll
    for (int i = 0; i < 4; ++i)
#pragma unroll
        for (int j = 0; j < 4; ++j)
#pragma unroll
            for (int r = 0; r < 4; ++r) {
                int row = brow + wy * 64 + i * 16 + quad * 4 + r;
                int col = bcol + wx * 64 + j * 16 + l16;
                C[(size_t)row * N + col] = acc[i][j][r];
            }
}

// ---------------- flash attention v12: 4 blocks/CU + MFMA l-sum -------------
// (unchanged — no longer the top dispatch)
__constant__ unsigned char c_sched[24] = {
    28, 61, 57, 58, 24, 53, 49, 20,
    62, 54, 50, 41, 42, 16, 45, 46,
     0,  4,  8, 12, 33, 37, 34, 38};

__global__ __launch_bounds__(256, 4) void attn_kernel(const bf16* __restrict__ qb,
                                                      const bf16* __restrict__ kb,
                                                      const bf16* __restrict__ vt,
                                                      float* __restrict__ Oacc,
                                                      float* __restrict__ Lacc,
                                                      bf16* __restrict__ conc) {
    __shared__ bf16 Ks[2][64 * 64];                // 2 x 8 KB
    __shared__ bf16 Vs[2][64 * 64];                // 2 x 8 KB
    __shared__ bf16 Pl[4][16 * 64];                // 8 KB (per-wave, shared g0/g1)
    const int bh = blockIdx.y;
    const int b = bh >> 4, h = bh & 15;

    const int e    = c_sched[blockIdx.x];
    const int tile = e >> 2, mode = e & 3;
    const int it0  = (mode == 2) ? tile + 1 : 0;
    const int it1  = (mode == 1) ? tile : 2 * tile + 1;
    const bool partial = (mode != 0);
    const int qbase = tile << 7;                   // 128 queries per tile

    const int tid = threadIdx.x;
    const int lane = tid & 63, wave = tid >> 6;
    const int l16 = lane & 15, quad = lane >> 4;
    const int qr0 = qbase + wave * 16;             // group0 query rows
    const int qr1 = qr0 + 64;                      // group1 query rows

    const bf16* Qp = qb + (size_t)bh * T_SEQ * DK;
    const bf16* Kp = kb + (size_t)bh * T_SEQ * DK;
    const bf16* Vp = vt + (size_t)bh * DK * T_SEQ;
    char* Pw = (char*)&Pl[wave][0];

    // ones B-fragment for the l row-sum MFMA
    const short one_bits = 0x3F80;
    const bf16x8 ones = {one_bits, one_bits, one_bits, one_bits,
                         one_bits, one_bits, one_bits, one_bits};

    // Q as B-operand: n = query = l16, k = dk = quad*8+j (+32 per kstep)
    bf16x8 qf[2][2];
#pragma unroll
    for (int s = 0; s < 2; ++s) {
        qf[0][s] = *(const bf16x8*)(Qp + (size_t)(qr0 + l16) * DK + s * 32 + quad * 8);
        qf[1][s] = *(const bf16x8*)(Qp + (size_t)(qr1 + l16) * DK + s * 32 + quad * 8);
    }

    // stage row-major 64x64 tile with XOR-swizzled 16B col-blocks
    auto stage = [&](int bb, int k0) {
        int j = tid;
#pragma unroll
        for (int i = 0; i < 2; ++i, j += 256) {
            int row = j >> 3, cbl = (j & 7) ^ ((j >> 3) & 7);
            load_lds16(Kp + (size_t)(k0 + row) * DK + cbl * 8, (char*)Ks[bb] + j * 16);
        }
        j = tid;
#pragma unroll
        for (int i = 0; i < 2; ++i, j += 256) {
            int row = j >> 3, cbl = (j & 7) ^ ((j >> 3) & 7);
            load_lds16(Vp + (size_t)row * T_SEQ + k0 + cbl * 8, (char*)Vs[bb] + j * 16);
        }
    };

    f32x4 o0[4] = {}, o1[4] = {};
    f32x4 ol0 = {}, ol1 = {};      // l row-sums (same C-rows as o*[j])
    const int sw0 = (quad ^ (l16 & 7)) * 8;
    const int sw1 = ((4 + quad) ^ (l16 & 7)) * 8;
    // P buffer addressing (bytes): row=l16 (128B), XOR-swizzled 16B blocks
    const int pw_wr_base = l16 * 128 + (quad & 1) * 8;   // + swizzled block
    const int pq = quad >> 1;

    int cur = 0;
    stage(0, it0 * 64);
    for (int it = it0; it <= it1; ++it) {
        __syncthreads();                      // drains DMA for cur + syncs waves
        if (it < it1) stage(cur ^ 1, (it + 1) * 64);

        const int k0 = it * 64;
        const bool skip0 = (k0 > qr0 + 15);             // wave-uniform
        const bool diag0 = (k0 + 63 > qr0) && !skip0;
        const bool diag1 = (k0 + 63 > qr1);             // skip1 never happens

        // S^T = K Q^T over 64 keys; kf fragments shared by both groups
        f32x4 s0[4] = {}, s1[4] = {};
        __builtin_amdgcn_s_setprio(1);
#pragma unroll
        for (int nt = 0; nt < 4; ++nt) {
            bf16x8 kf0 = *(const bf16x8*)(Ks[cur] + (nt * 16 + l16) * 64 + sw0);
            bf16x8 kf1 = *(const bf16x8*)(Ks[cur] + (nt * 16 + l16) * 64 + sw1);
            if (!skip0) {
                s0[nt] = __builtin_amdgcn_mfma_f32_16x16x32_bf16(kf0, qf[0][0], s0[nt], 0, 0, 0);
                s0[nt] = __builtin_amdgcn_mfma_f32_16x16x32_bf16(kf1, qf[0][1], s0[nt], 0, 0, 0);
            }
            s1[nt] = __builtin_amdgcn_mfma_f32_16x16x32_bf16(kf0, qf[1][0], s1[nt], 0, 0, 0);
            s1[nt] = __builtin_amdgcn_mfma_f32_16x16x32_bf16(kf1, qf[1][1], s1[nt], 0, 0, 0);
        }
        __builtin_amdgcn_s_setprio(0);

        // ---- group 0: exp -> P buffer -> PV (+ l-sum MFMA) ----
        if (!skip0) {
#pragma unroll
            for (int nt = 0; nt < 4; ++nt) {
                union { bf16 hv[4]; uint2 u; } pk;
#pragma unroll
                for (int r = 0; r < 4; ++r) {
                    float v = s0[nt][r];
                    if (diag0 && (k0 + nt * 16 + quad * 4 + r > qr0 + l16)) v = -30.0f;
                    pk.hv[r] = __float2bfloat16(exp2f(v));
                }
                *(uint2*)(Pw + pw_wr_base + (((nt * 2 + pq) ^ (l16 & 7)) << 4)) = pk.u;
            }
            __builtin_amdgcn_s_setprio(1);
#pragma unroll
            for (int ks = 0; ks < 2; ++ks) {
                bf16x8 pf = *(const bf16x8*)(Pw + l16 * 128 + (((ks * 4 + quad) ^ (l16 & 7)) << 4));
                const int sw = ks ? sw1 : sw0;
                ol0 = __builtin_amdgcn_mfma_f32_16x16x32_bf16(pf, ones, ol0, 0, 0, 0);
#pragma unroll
                for (int j = 0; j < 4; ++j) {
                    bf16x8 vf = *(const bf16x8*)(Vs[cur] + (j * 16 + l16) * 64 + sw);
                    o0[j] = __builtin_amdgcn_mfma_f32_16x16x32_bf16(pf, vf, o0[j], 0, 0, 0);
                }
            }
            __builtin_amdgcn_s_setprio(0);
        }

        // ---- group 1: exp -> P buffer (reused; per-wave DS pipe is in-order,
        // so these writes cannot pass g0's pf reads) -> PV (+ l-sum MFMA) ----
#pragma unroll
        for (int nt = 0; nt < 4; ++nt) {
            union { bf16 hv[4]; uint2 u; } pk;
#pragma unroll
            for (int r = 0; r < 4; ++r) {
                float v = s1[nt][r];
                if (diag1 && (k0 + nt * 16 + quad * 4 + r > qr1 + l16)) v = -30.0f;
                pk.hv[r] = __float2bfloat16(exp2f(v));
            }
            *(uint2*)(Pw + pw_wr_base + (((nt * 2 + pq) ^ (l16 & 7)) << 4)) = pk.u;
        }
        __builtin_amdgcn_s_setprio(1);
#pragma unroll
        for (int ks = 0; ks < 2; ++ks) {
            bf16x8 pf = *(const bf16x8*)(Pw + l16 * 128 + (((ks * 4 + quad) ^ (l16 & 7)) << 4));
            const int sw = ks ? sw1 : sw0;
            ol1 = __builtin_amdgcn_mfma_f32_16x16x32_bf16(pf, ones, ol1, 0, 0, 0);
#pragma unroll
            for (int j = 0; j < 4; ++j) {
                bf16x8 vf = *(const bf16x8*)(Vs[cur] + (j * 16 + l16) * 64 + sw);
                o1[j] = __builtin_amdgcn_mfma_f32_16x16x32_bf16(pf, vf, o1[j], 0, 0, 0);
            }
        }
        __builtin_amdgcn_s_setprio(0);
        cur ^= 1;
    }

    // epilogue: ol*[r] is the full l for query qr + quad*4 + r (no shuffles)
#pragma unroll
    for (int g = 0; g < 2; ++g) {
        const f32x4* op = g ? o1 : o0;
        const f32x4 lv = g ? ol1 : ol0;
        const int qr = g ? qr1 : qr0;
        if (!partial) {
#pragma unroll
            for (int r = 0; r < 4; ++r) {
                float inv_l = 1.0f / lv[r];
                int t = qr + quad * 4 + r;
#pragma unroll
                for (int j = 0; j < 4; ++j)
                    conc[((size_t)b * T_SEQ + t) * DMODEL + h * DK + j * 16 + l16] =
                        __float2bfloat16(op[j][r] * inv_l);
            }
        } else {
#pragma unroll
            for (int r = 0; r < 4; ++r) {
                int q = qr + quad * 4 + r;
                if (l16 == 0)
                    atomicAdd(&Lacc[(size_t)bh * 1024 + q - 1024], lv[r]);
                float* Ob = Oacc + ((size_t)bh * 1024 + q - 1024) * DK;
#pragma unroll
                for (int j = 0; j < 4; ++j)
                    atomicAdd(&Ob[j * 16 + l16], op[j][r]);
            }
        }
    }
}

// ---------------- normalize + concat (only q in [1024, 2048)) ----------------
__global__ void attn_finalize(const float* __restrict__ Oacc, const float* __restrict__ Lacc,
                              bf16* __restrict__ conc) {
    int i4 = blockIdx.x * blockDim.x + threadIdx.x;   // float4 units, 0..512K-1
    if (i4 >= (1 << 19)) return;
    int bhq = i4 >> 4;          // bh*1024 + q1
    int d4  = i4 & 15;
    int bh = bhq >> 10, q1 = bhq & 1023;
    int b = bh >> 4, h = bh & 15;
    int q = 1024 + q1;
    float inv = 1.0f / Lacc[bhq];
    float4 o4 = ((const float4*)Oacc)[i4];
    ushort4 u;
    u.x = __bfloat16_as_ushort(__float2bfloat16(o4.x * inv));
    u.y = __bfloat16_as_ushort(__float2bfloat16(o4.y * inv));
    u.z = __bfloat16_as_ushort(__float2bfloat16(o4.z * inv));
    u.w = __bfloat16_as_ushort(__float2bfloat16(o4.w * inv));
    *(ushort4*)&conc[((size_t)(b * T_SEQ + q)) * DMODEL + h * DK + d4 * 4] = u;
}

extern "C" void kernel_launch(void* const* d_in, const int* in_sizes, int n_in,
                              void* d_out, int out_size, void* d_ws, size_t ws_size,
                              hipStream_t stream) {
    const float* x  = (const float*)d_in[0];
    const float* wq = (const float*)d_in[1];
    const float* wk = (const float*)d_in[2];
    const float* wv = (const float*)d_in[3];
    const float* wo = (const float*)d_in[4];
    float* out = (float*)d_out;

    char* ws = (char*)d_ws;
    bf16* xb    = (bf16*)(ws);                      // 8 MiB  (4096x1024)
    bf16* wqkvb = (bf16*)(ws + (8ull << 20));       // 6 MiB  (3072x1024)
    bf16* wob   = (bf16*)(ws + (14ull << 20));      // 2 MiB  (1024x1024)
    bf16* qb    = (bf16*)(ws + (40ull << 20));      // 8 MiB
    bf16* kb    = (bf16*)(ws + (48ull << 20));      // 8 MiB
    bf16* vt    = (bf16*)(ws + (56ull << 20));      // 8 MiB
    bf16* conc  = (bf16*)(ws + (16ull << 20));      // 8 MiB
    float* Oacc = (float*)(ws + (24ull << 20));     // 8 MiB
    float* Lacc = (float*)(ws + (32ull << 20));     // 128 KiB

    cvt_all<<<8192, 256, 0, stream>>>(x, wq, wk, wv, wo, xb, wqkvb, wob);
    gemm_qkv_rope<<<dim3(24, 32), 256, 0, stream>>>(xb, wqkvb, qb, kb, vt);

    hipMemsetAsync(Oacc, 0, (8ull << 20) + 32 * 1024 * sizeof(float), stream);
    attn_kernel<<<dim3(24, 32), 256, 0, stream>>>(qb, kb, vt, Oacc, Lacc, conc);
    attn_finalize<<<2048, 256, 0, stream>>>(Oacc, Lacc, conc);

    gemm_bt<<<dim3(8, 32), 256, 0, stream>>>(conc, wob, out, 4096, 1024, 1024);
}